// Round 7
// baseline (759.091 us; speedup 1.0000x reference)
//
#include <hip/hip_runtime.h>
#include <hip/hip_bf16.h>

typedef __hip_bfloat16 bf16;
typedef __attribute__((ext_vector_type(8))) short short8;
typedef __attribute__((ext_vector_type(4))) float f32x4;

#define SEQ    4096
#define DMODEL 1024
#define NHEAD  16
#define DKH    64

#define LSTRIDE 72   // legacy fp32-path LDS row stride (shorts)

__device__ __forceinline__ float ldf(const float* p, size_t i) { return p[i]; }
__device__ __forceinline__ float ldf(const bf16*  p, size_t i) { return __bfloat162float(p[i]); }
__device__ __forceinline__ void stf(float* p, size_t i, float v) { p[i] = v; }
__device__ __forceinline__ void stf(bf16*  p, size_t i, float v) { p[i] = __float2bfloat16(v); }

__device__ __forceinline__ short f2bs(float v) {
    bf16 b = __float2bfloat16(v);
    return *(short*)&b;
}
__device__ __forceinline__ float bs2f(short s) {
    unsigned u = ((unsigned)(unsigned short)s) << 16;
    return __uint_as_float(u);
}

__device__ __forceinline__ short8 lda8(const bf16* p, size_t i) {
    return *(const short8*)(p + i);
}
__device__ __forceinline__ short8 lda8(const float* p, size_t i) {
    float4 a = *(const float4*)(p + i);
    float4 b = *(const float4*)(p + i + 4);
    short8 r;
    r[0] = f2bs(a.x); r[1] = f2bs(a.y); r[2] = f2bs(a.z); r[3] = f2bs(a.w);
    r[4] = f2bs(b.x); r[5] = f2bs(b.y); r[6] = f2bs(b.z); r[7] = f2bs(b.w);
    return r;
}

// async 16B global -> LDS (dest = wave-uniform base + lane*16)
__device__ __forceinline__ void g2l16(const void* g, void* l) {
    __builtin_amdgcn_global_load_lds(
        (const __attribute__((address_space(1))) unsigned int*)g,
        (__attribute__((address_space(3))) unsigned int*)l, 16, 0, 0);
}

// bf16 (flag=1) vs fp32 (flag=0) storage detector (worked rounds 2-6).
__global__ void detect_dtype(const unsigned short* __restrict__ x, int* __restrict__ flag) {
    int lane = threadIdx.x;
    int cnt = 0;
    for (int i = lane; i < 512; i += 64) {
        int e = (x[i] >> 7) & 0xFF;
        cnt += (e >= 100 && e <= 140) ? 1 : 0;
    }
    #pragma unroll
    for (int off = 32; off; off >>= 1) cnt += __shfl_xor(cnt, off, 64);
    if (lane == 0) *flag = (cnt >= 400) ? 1 : 0;
}

// sim-tile raw vector load types (load raw early, convert at use)
template <typename TS> struct SimT;
template <> struct SimT<bf16>  { using V = short4; };
template <> struct SimT<float> { using V = float4; };

__device__ __forceinline__ f32x4 cvt4(short4 s) {
    f32x4 r;
    r[0] = bs2f(s.x); r[1] = bs2f(s.y); r[2] = bs2f(s.z); r[3] = bs2f(s.w);
    return r;
}
__device__ __forceinline__ f32x4 cvt4(float4 v) {
    f32x4 r; r[0] = v.x; r[1] = v.y; r[2] = v.z; r[3] = v.w; return r;
}

// ---------------- bf16 GEMM body: DMA staging + XOR-swizzled LDS, 128x128 tile ----------------
template <typename TC>
__device__ void gemm_dma_body(const bf16* __restrict__ A, const bf16* __restrict__ B,
                              const bf16* __restrict__ bias, TC* __restrict__ C,
                              int m0, int n0, int M, int N, int K, bool transc, float cscale,
                              short* As, short* Bs) {
    const int tid = threadIdx.x;
    const int w = tid >> 6, lane = tid & 63, q = lane >> 4, c = lane & 15;
    const int mb = 64 * (w & 1), nb = 64 * (w >> 1);

    f32x4 acc[4][4] = {};

    for (int k0 = 0; k0 < K; k0 += 64) {
        __syncthreads();
        #pragma unroll
        for (int i = 0; i < 4; ++i) {
            int p = i * 256 + tid;
            int row = p >> 3, pc = p & 7, gc = pc ^ (row & 7);
            g2l16(A + (size_t)(m0 + row) * K + k0 + gc * 8, As + (size_t)p * 8);
            g2l16(B + (size_t)(n0 + row) * K + k0 + gc * 8, Bs + (size_t)p * 8);
        }
        __syncthreads();
        #pragma unroll
        for (int kh = 0; kh < 2; ++kh) {
            short8 af[4], bfr[4];
            #pragma unroll
            for (int i = 0; i < 4; ++i) {
                int row = mb + i * 16 + c;
                af[i] = *(const short8*)&As[row * 64 + (((kh * 4 + q) ^ (row & 7)) << 3)];
            }
            #pragma unroll
            for (int j = 0; j < 4; ++j) {
                int row = nb + j * 16 + c;
                bfr[j] = *(const short8*)&Bs[row * 64 + (((kh * 4 + q) ^ (row & 7)) << 3)];
            }
            #pragma unroll
            for (int i = 0; i < 4; ++i)
                #pragma unroll
                for (int j = 0; j < 4; ++j)
                    acc[i][j] = __builtin_amdgcn_mfma_f32_16x16x32_bf16(af[i], bfr[j], acc[i][j], 0, 0, 0);
        }
    }

    #pragma unroll
    for (int j = 0; j < 4; ++j) {
        int n = n0 + nb + j * 16 + c;
        float bj = __bfloat162float(bias[n]);
        #pragma unroll
        for (int i = 0; i < 4; ++i) {
            if (transc) {
                short4 pk;
                pk.x = f2bs((acc[i][j][0] + bj) * cscale);
                pk.y = f2bs((acc[i][j][1] + bj) * cscale);
                pk.z = f2bs((acc[i][j][2] + bj) * cscale);
                pk.w = f2bs((acc[i][j][3] + bj) * cscale);
                int m = m0 + mb + i * 16 + q * 4;
                *(short4*)&((bf16*)C)[(size_t)n * M + m] = pk;
            } else {
                #pragma unroll
                for (int t = 0; t < 4; ++t) {
                    int m = m0 + mb + i * 16 + q * 4 + t;
                    stf(C, (size_t)m * N + n, (acc[i][j][t] + bj) * cscale);
                }
            }
        }
    }
}

// 64(M)x128(N) tile variant for the out-projection.
template <typename TC>
__device__ void gemm_dma64_body(const bf16* __restrict__ A, const bf16* __restrict__ B,
                                const bf16* __restrict__ bias, TC* __restrict__ C,
                                int m0, int n0, int M, int N, int K,
                                short* As, short* Bs) {
    const int tid = threadIdx.x;
    const int w = tid >> 6, lane = tid & 63, q = lane >> 4, c = lane & 15;
    const int nb = 32 * w;

    f32x4 acc[4][2] = {};

    for (int k0 = 0; k0 < K; k0 += 64) {
        __syncthreads();
        #pragma unroll
        for (int i = 0; i < 2; ++i) {
            int p = i * 256 + tid;
            int row = p >> 3, pc = p & 7, gc = pc ^ (row & 7);
            g2l16(A + (size_t)(m0 + row) * K + k0 + gc * 8, As + (size_t)p * 8);
        }
        #pragma unroll
        for (int i = 0; i < 4; ++i) {
            int p = i * 256 + tid;
            int row = p >> 3, pc = p & 7, gc = pc ^ (row & 7);
            g2l16(B + (size_t)(n0 + row) * K + k0 + gc * 8, Bs + (size_t)p * 8);
        }
        __syncthreads();
        #pragma unroll
        for (int kh = 0; kh < 2; ++kh) {
            short8 af[4], bfr[2];
            #pragma unroll
            for (int i = 0; i < 4; ++i) {
                int row = i * 16 + c;
                af[i] = *(const short8*)&As[row * 64 + (((kh * 4 + q) ^ (row & 7)) << 3)];
            }
            #pragma unroll
            for (int j = 0; j < 2; ++j) {
                int row = nb + j * 16 + c;
                bfr[j] = *(const short8*)&Bs[row * 64 + (((kh * 4 + q) ^ (row & 7)) << 3)];
            }
            #pragma unroll
            for (int i = 0; i < 4; ++i)
                #pragma unroll
                for (int j = 0; j < 2; ++j)
                    acc[i][j] = __builtin_amdgcn_mfma_f32_16x16x32_bf16(af[i], bfr[j], acc[i][j], 0, 0, 0);
        }
    }

    #pragma unroll
    for (int j = 0; j < 2; ++j) {
        int n = n0 + nb + j * 16 + c;
        float bj = __bfloat162float(bias[n]);
        #pragma unroll
        for (int i = 0; i < 4; ++i)
            #pragma unroll
            for (int t = 0; t < 4; ++t) {
                int m = m0 + i * 16 + q * 4 + t;
                stf(C, (size_t)m * N + n, acc[i][j][t] + bj);
            }
    }
}

// ---------------- legacy GEMM body (fp32 inputs; VALU staging) ----------------
template <typename TA, typename TB, typename TC>
__device__ void gemm_legacy_body(const TA* __restrict__ A, const TB* __restrict__ B,
                                 const TB* __restrict__ bias, TC* __restrict__ C,
                                 int m0, int n0, int M, int N, int K, bool transc, float cscale,
                                 short* As, short* Bs) {
    const int tid = threadIdx.x;
    const int w = tid >> 6, lane = tid & 63, q = lane >> 4, c = lane & 15;
    const int mb = 64 * (w & 1), nb = 64 * (w >> 1);

    f32x4 acc[4][4] = {};

    for (int k0 = 0; k0 < K; k0 += 64) {
        __syncthreads();
        #pragma unroll
        for (int i = 0; i < 4; ++i) {
            int ch = tid + 256 * i;
            int r = ch >> 3, c8 = (ch & 7) * 8;
            *(short8*)&As[r * LSTRIDE + c8] = lda8(A, (size_t)(m0 + r) * K + k0 + c8);
            *(short8*)&Bs[r * LSTRIDE + c8] = lda8(B, (size_t)(n0 + r) * K + k0 + c8);
        }
        __syncthreads();
        #pragma unroll
        for (int kh = 0; kh < 2; ++kh) {
            const int kk = kh * 32 + q * 8;
            short8 af[4], bfr[4];
            #pragma unroll
            for (int i = 0; i < 4; ++i)
                af[i] = *(const short8*)&As[(mb + i * 16 + c) * LSTRIDE + kk];
            #pragma unroll
            for (int j = 0; j < 4; ++j)
                bfr[j] = *(const short8*)&Bs[(nb + j * 16 + c) * LSTRIDE + kk];
            #pragma unroll
            for (int i = 0; i < 4; ++i)
                #pragma unroll
                for (int j = 0; j < 4; ++j)
                    acc[i][j] = __builtin_amdgcn_mfma_f32_16x16x32_bf16(af[i], bfr[j], acc[i][j], 0, 0, 0);
        }
    }

    #pragma unroll
    for (int j = 0; j < 4; ++j) {
        int n = n0 + nb + j * 16 + c;
        float bj = ldf(bias, (size_t)n);
        #pragma unroll
        for (int i = 0; i < 4; ++i) {
            if (transc) {
                short4 pk;
                pk.x = f2bs((acc[i][j][0] + bj) * cscale);
                pk.y = f2bs((acc[i][j][1] + bj) * cscale);
                pk.z = f2bs((acc[i][j][2] + bj) * cscale);
                pk.w = f2bs((acc[i][j][3] + bj) * cscale);
                int m = m0 + mb + i * 16 + q * 4;
                *(short4*)&((bf16*)C)[(size_t)n * M + m] = pk;
            } else {
                #pragma unroll
                for (int t = 0; t < 4; ++t) {
                    int m = m0 + mb + i * 16 + q * 4 + t;
                    stf(C, (size_t)m * N + n, (acc[i][j][t] + bj) * cscale);
                }
            }
        }
    }
}

// Fused QKV projection. Q output pre-scaled by 1/8 (folded softmax scale).
__global__ __launch_bounds__(256)
void gemm_qkv(const void* __restrict__ x,
              const void* __restrict__ wq, const void* __restrict__ bq,
              const void* __restrict__ wk, const void* __restrict__ bk,
              const void* __restrict__ wv, const void* __restrict__ bv,
              bf16* __restrict__ Q, bf16* __restrict__ K, bf16* __restrict__ Vt,
              const int* __restrict__ flag) {
    __shared__ __align__(16) short As[128 * LSTRIDE];
    __shared__ __align__(16) short Bs[128 * LSTRIDE];
    const int sel = blockIdx.y >> 3;
    const int m0 = blockIdx.x * 128, n0 = (blockIdx.y & 7) * 128;
    const void* B  = (sel == 0) ? wq : (sel == 1) ? wk : wv;
    const void* bi = (sel == 0) ? bq : (sel == 1) ? bk : bv;
    bf16* C        = (sel == 0) ? Q  : (sel == 1) ? K  : Vt;
    const bool tr = (sel == 2);
    const float cs = (sel == 0) ? 0.125f : 1.0f;
    if (*flag)
        gemm_dma_body<bf16>((const bf16*)x, (const bf16*)B, (const bf16*)bi, C,
                            m0, n0, SEQ, DMODEL, DMODEL, tr, cs, As, Bs);
    else
        gemm_legacy_body<float, float, bf16>((const float*)x, (const float*)B, (const float*)bi, C,
                                             m0, n0, SEQ, DMODEL, DMODEL, tr, cs, As, Bs);
}

__global__ __launch_bounds__(256)
void gemm_out_k(const bf16* __restrict__ A, const void* __restrict__ B,
                const void* __restrict__ bias, void* __restrict__ C,
                const int* __restrict__ flag, int M, int N, int K) {
    __shared__ __align__(16) short As[128 * LSTRIDE];
    __shared__ __align__(16) short Bs[128 * LSTRIDE];
    if (*flag) {
        gemm_dma64_body<bf16>(A, (const bf16*)B, (const bf16*)bias, (bf16*)C,
                              blockIdx.x * 64, blockIdx.y * 128, M, N, K, As, Bs);
    } else {
        if (blockIdx.x >= (unsigned)(M / 128)) return;
        gemm_legacy_body<bf16, float, float>(A, (const float*)B, (const float*)bias, (float*)C,
                                             blockIdx.x * 128, blockIdx.y * 128, M, N, K, false, 1.0f, As, Bs);
    }
}

// ---------------- flash attention v7: S^T form, zero-LDS loop, 1-deep pipeline ----------
// Per block: 4 waves x 32 q-rows, one head, K-range = NT tiles of 64.
// S^T = K·Q^T (sim^T enters via the MFMA C operand; Q pre-scaled by 1/8).
// P^T (C-layout) feeds PV directly as B-operand under k-slot permutation sigma(q,j);
// V^T A-fragments load with the same sigma. O accumulated transposed, stored direct.
template <typename TS, bool SPLIT, int NT>
__device__ void flash_body(const bf16* __restrict__ Qg, const bf16* __restrict__ Kg,
                           const bf16* __restrict__ VtG, const TS* __restrict__ sim,
                           bf16* __restrict__ O, float* __restrict__ Opart,
                           float* __restrict__ Lpart) {
    using SV = typename SimT<TS>::V;
    const int tid = threadIdx.x;
    const int w = tid >> 6, lane = tid & 63, q = lane >> 4, c = lane & 15;
    const int hd = blockIdx.y * DKH;
    const int kz = SPLIT ? blockIdx.z : 0;
    const int t0 = kz * NT;
    const int r0 = blockIdx.x * 128 + w * 32;

    // Q fragments as B-operand: n = q-row (lanes), k = head-dim (regs)
    short8 qf[2][2];
    #pragma unroll
    for (int m = 0; m < 2; ++m)
        #pragma unroll
        for (int kc = 0; kc < 2; ++kc)
            qf[m][kc] = *(const short8*)&Qg[(size_t)(r0 + m * 16 + c) * DMODEL + hd + kc * 32 + q * 8];

    // double-buffered K A-frags and raw sim^T C-frags
    short8 Ka[2][4][2];
    SV     sb[2][2][4];

    #pragma unroll
    for (int f = 0; f < 4; ++f)
        #pragma unroll
        for (int kc = 0; kc < 2; ++kc)
            Ka[0][f][kc] = *(const short8*)&Kg[(size_t)(t0 * 64 + f * 16 + c) * DMODEL + hd + kc * 32 + q * 8];
    #pragma unroll
    for (int m = 0; m < 2; ++m)
        #pragma unroll
        for (int f = 0; f < 4; ++f)
            sb[0][m][f] = *(const SV*)&sim[(size_t)(r0 + m * 16 + c) * SEQ + t0 * 64 + f * 16 + q * 4];

    f32x4 accOT[4][2] = {};   // [f'=d-block][m]: O^T tiles
    float Lp[2] = {};         // per-lane row-sum partials (row = 16m + c)

    for (int tp = 0; tp < NT; tp += 2) {
        #pragma unroll
        for (int sub = 0; sub < 2; ++sub) {
            const int cur = sub, nxt = sub ^ 1;
            const int t = tp + sub;
            const int k0 = (t0 + t) * 64;
            const int tn = (t + 1 < NT) ? t + 1 : 0;
            const int kn = (t0 + tn) * 64;

            // prefetch t+1 (K + sim), no wait
            #pragma unroll
            for (int f = 0; f < 4; ++f)
                #pragma unroll
                for (int kc = 0; kc < 2; ++kc)
                    Ka[nxt][f][kc] = *(const short8*)&Kg[(size_t)(kn + f * 16 + c) * DMODEL + hd + kc * 32 + q * 8];
            #pragma unroll
            for (int m = 0; m < 2; ++m)
                #pragma unroll
                for (int f = 0; f < 4; ++f)
                    sb[nxt][m][f] = *(const SV*)&sim[(size_t)(r0 + m * 16 + c) * SEQ + kn + f * 16 + q * 4];

            // V^T A-frags for t (permuted k-slots: j0..3 -> col cc*32+4q.., j4..7 -> col cc*32+16+4q..)
            short4 vt0[4][2], vt1[4][2];
            #pragma unroll
            for (int fp = 0; fp < 4; ++fp)
                #pragma unroll
                for (int cc = 0; cc < 2; ++cc) {
                    const bf16* vb = &VtG[(size_t)(hd + fp * 16 + c) * SEQ + k0 + cc * 32 + 4 * q];
                    vt0[fp][cc] = *(const short4*)vb;
                    vt1[fp][cc] = *(const short4*)(vb + 16);
                }

            // S^T = K·Q^T + sim^T  (acc initialized with sim)
            f32x4 st[4][2];
            #pragma unroll
            for (int f = 0; f < 4; ++f)
                #pragma unroll
                for (int m = 0; m < 2; ++m) {
                    f32x4 a = cvt4(sb[cur][m][f]);
                    a = __builtin_amdgcn_mfma_f32_16x16x32_bf16(Ka[cur][f][0], qf[m][0], a, 0, 0, 0);
                    a = __builtin_amdgcn_mfma_f32_16x16x32_bf16(Ka[cur][f][1], qf[m][1], a, 0, 0, 0);
                    st[f][m] = a;
                }

            // p = exp(s); pack P^T B-frags (k-slots j0..3 = tile 2cc, j4..7 = tile 2cc+1)
            short8 bp[2][2];
            #pragma unroll
            for (int m = 0; m < 2; ++m)
                #pragma unroll
                for (int cc = 0; cc < 2; ++cc) {
                    #pragma unroll
                    for (int h = 0; h < 2; ++h) {
                        const int f = 2 * cc + h;
                        #pragma unroll
                        for (int i = 0; i < 4; ++i) {
                            float p = __expf(st[f][m][i]);
                            Lp[m] += p;
                            bp[m][cc][4 * h + i] = f2bs(p);
                        }
                    }
                }

            // O^T += V^T · P^T
            #pragma unroll
            for (int cc = 0; cc < 2; ++cc)
                #pragma unroll
                for (int fp = 0; fp < 4; ++fp) {
                    short8 av;
                    #pragma unroll
                    for (int i = 0; i < 4; ++i) { av[i] = ((short*)&vt0[fp][cc])[i]; av[4 + i] = ((short*)&vt1[fp][cc])[i]; }
                    #pragma unroll
                    for (int m = 0; m < 2; ++m)
                        accOT[fp][m] = __builtin_amdgcn_mfma_f32_16x16x32_bf16(av, bp[m][cc], accOT[fp][m], 0, 0, 0);
                }
        }
    }

    // reduce row sums across the 4 quads (lanes c hold row 16m+c in every quad)
    #pragma unroll
    for (int m = 0; m < 2; ++m) {
        Lp[m] += __shfl_xor(Lp[m], 16, 64);
        Lp[m] += __shfl_xor(Lp[m], 32, 64);
    }

    #pragma unroll
    for (int m = 0; m < 2; ++m) {
        const int row = r0 + m * 16 + c;
        if (SPLIT) {
            if (q == 0)
                Lpart[((size_t)kz * NHEAD + blockIdx.y) * SEQ + row] = Lp[m];
            #pragma unroll
            for (int fp = 0; fp < 4; ++fp)
                *(float4*)&Opart[((size_t)kz * SEQ + row) * DMODEL + hd + fp * 16 + q * 4] =
                    *(float4*)&accOT[fp][m];
        } else {
            float inv = 1.f / Lp[m];
            #pragma unroll
            for (int fp = 0; fp < 4; ++fp) {
                short4 pk;
                pk.x = f2bs(accOT[fp][m][0] * inv);
                pk.y = f2bs(accOT[fp][m][1] * inv);
                pk.z = f2bs(accOT[fp][m][2] * inv);
                pk.w = f2bs(accOT[fp][m][3] * inv);
                *(short4*)&O[(size_t)row * DMODEL + hd + fp * 16 + q * 4] = pk;
            }
        }
    }
}

__global__ __launch_bounds__(256)
void flash_split(const bf16* __restrict__ Q, const bf16* __restrict__ K,
                 const bf16* __restrict__ Vt, const void* __restrict__ sim,
                 float* __restrict__ Opart, float* __restrict__ Lpart,
                 const int* __restrict__ flag) {
    if (*flag)
        flash_body<bf16, true, SEQ / 128>(Q, K, Vt, (const bf16*)sim, nullptr, Opart, Lpart);
    else
        flash_body<float, true, SEQ / 128>(Q, K, Vt, (const float*)sim, nullptr, Opart, Lpart);
}

__global__ __launch_bounds__(256)
void flash_ns(const bf16* __restrict__ Q, const bf16* __restrict__ K,
              const bf16* __restrict__ Vt, const void* __restrict__ sim,
              bf16* __restrict__ O, const int* __restrict__ flag) {
    if (*flag)
        flash_body<bf16, false, SEQ / 64>(Q, K, Vt, (const bf16*)sim, O, nullptr, nullptr);
    else
        flash_body<float, false, SEQ / 64>(Q, K, Vt, (const float*)sim, O, nullptr, nullptr);
}

// O = (O0 + O1) / (L0 + L1), bf16 out. One float4 per thread.
__global__ __launch_bounds__(256)
void combine_k(const float* __restrict__ Opart, const float* __restrict__ Lpart,
               bf16* __restrict__ O) {
    size_t idx = (size_t)blockIdx.x * 256 + threadIdx.x;
    size_t base = idx * 4;
    int row = (int)(base >> 10);
    int d = (int)(base & 1023);
    int h = d >> 6;
    const float4 a = *(const float4*)&Opart[base];
    const float4 b = *(const float4*)&Opart[(size_t)SEQ * DMODEL + base];
    float L = Lpart[(size_t)h * SEQ + row] + Lpart[(size_t)(NHEAD + h) * SEQ + row];
    float inv = 1.f / L;
    short4 pk;
    pk.x = f2bs((a.x + b.x) * inv);
    pk.y = f2bs((a.y + b.y) * inv);
    pk.z = f2bs((a.z + b.z) * inv);
    pk.w = f2bs((a.w + b.w) * inv);
    *(short4*)&O[base] = pk;
}

extern "C" void kernel_launch(void* const* d_in, const int* in_sizes, int n_in,
                              void* d_out, int out_size, void* d_ws, size_t ws_size,
                              hipStream_t stream) {
    int* flagw = (int*)d_ws;
    const int* flag = (const int*)d_ws;
    bf16* Q  = (bf16*)((char*)d_ws + 256);
    bf16* K  = Q + (size_t)SEQ * DMODEL;
    bf16* Vt = K + (size_t)SEQ * DMODEL;   // transposed: [DMODEL][SEQ]
    bf16* O  = Vt + (size_t)SEQ * DMODEL;
    float* Lpart = (float*)(O + (size_t)SEQ * DMODEL);       // [2][NHEAD][SEQ]
    float* Opart = Lpart + 2 * (size_t)NHEAD * SEQ;          // [2][SEQ][DMODEL]

    const size_t need = 256 + 4 * (size_t)SEQ * DMODEL * sizeof(bf16)
                      + 2 * (size_t)NHEAD * SEQ * sizeof(float)
                      + 2 * (size_t)SEQ * DMODEL * sizeof(float);
    const bool split = (ws_size >= need);

    detect_dtype<<<1, 64, 0, stream>>>((const unsigned short*)d_in[0], flagw);

    dim3 blk(256);
    gemm_qkv<<<dim3(SEQ / 128, 24), blk, 0, stream>>>(
        d_in[0], d_in[2], d_in[3], d_in[4], d_in[5], d_in[6], d_in[7], Q, K, Vt, flag);

    if (split) {
        flash_split<<<dim3(SEQ / 128, NHEAD, 2), blk, 0, stream>>>(
            Q, K, Vt, d_in[1], Opart, Lpart, flag);
        combine_k<<<dim3(SEQ * DMODEL / 1024), blk, 0, stream>>>(Opart, Lpart, O);
    } else {
        flash_ns<<<dim3(SEQ / 128, NHEAD), blk, 0, stream>>>(Q, K, Vt, d_in[1], O, flag);
    }

    gemm_out_k<<<dim3(SEQ / 64, DMODEL / 128), blk, 0, stream>>>(
        O, d_in[8], d_in[9], d_out, flag, SEQ, DMODEL, DMODEL);
}